// Round 1
// baseline (560.020 us; speedup 1.0000x reference)
//
#include <hip/hip_runtime.h>
#include <hip/hip_bf16.h>

// GCN: 3x (GEMM + CSR aggregation) + pool + MLP, fp32 throughout.

__global__ __launch_bounds__(256) void k_zero(int* __restrict__ p, int n) {
  int i = blockIdx.x * blockDim.x + threadIdx.x;
  for (; i < n; i += gridDim.x * blockDim.x) p[i] = 0;
}

__global__ __launch_bounds__(256) void k_count(const int* __restrict__ dst, int* __restrict__ cnt, int e_count) {
  int e = blockIdx.x * blockDim.x + threadIdx.x;
  if (e < e_count) atomicAdd(&cnt[dst[e]], 1);
}

__global__ __launch_bounds__(256) void k_dinv(const int* __restrict__ cnt, float* __restrict__ dinv, int n) {
  int v = blockIdx.x * blockDim.x + threadIdx.x;
  if (v < n) dinv[v] = rsqrtf((float)cnt[v] + 1.0f);
}

// ---- hierarchical exclusive scan over cnt[0..n) -> offsets[0..n], offsets[n]=total
__global__ __launch_bounds__(256) void k_scan1(const int* __restrict__ cnt, int n, int* __restrict__ bsum) {
  __shared__ int s[256];
  int b = blockIdx.x, t = threadIdx.x;
  int base = b * 1024;
  int sum = 0;
  #pragma unroll
  for (int i = 0; i < 4; ++i) {
    int idx = base + t + i * 256;
    if (idx < n) sum += cnt[idx];
  }
  s[t] = sum; __syncthreads();
  for (int off = 128; off > 0; off >>= 1) {
    if (t < off) s[t] += s[t + off];
    __syncthreads();
  }
  if (t == 0) bsum[b] = s[0];
}

__global__ __launch_bounds__(128) void k_scan2(int* __restrict__ bsum, int nb, int* __restrict__ total_out) {
  // nb <= 128 (N=100000 -> 98 blocks of 1024)
  __shared__ int sh[128];
  int t = threadIdx.x;
  sh[t] = (t < nb) ? bsum[t] : 0;
  __syncthreads();
  for (int off = 1; off < 128; off <<= 1) {
    int x = sh[t];
    int y = (t >= off) ? sh[t - off] : 0;
    __syncthreads();
    sh[t] = x + y;
    __syncthreads();
  }
  if (t < nb) bsum[t] = (t == 0) ? 0 : sh[t - 1];
  if (t == 0) *total_out = sh[127];
}

__global__ __launch_bounds__(256) void k_scan3(const int* __restrict__ cnt, int n,
                                               const int* __restrict__ bsum_ex, int* __restrict__ offsets) {
  __shared__ int sh[256];
  int b = blockIdx.x, t = threadIdx.x;
  int base = b * 1024 + t * 4;
  int v0 = (base + 0 < n) ? cnt[base + 0] : 0;
  int v1 = (base + 1 < n) ? cnt[base + 1] : 0;
  int v2 = (base + 2 < n) ? cnt[base + 2] : 0;
  int v3 = (base + 3 < n) ? cnt[base + 3] : 0;
  sh[t] = v0 + v1 + v2 + v3;
  __syncthreads();
  for (int off = 1; off < 256; off <<= 1) {
    int x = sh[t];
    int y = (t >= off) ? sh[t - off] : 0;
    __syncthreads();
    sh[t] = x + y;
    __syncthreads();
  }
  int run = bsum_ex[b] + ((t == 0) ? 0 : sh[t - 1]);
  if (base + 0 < n) offsets[base + 0] = run; run += v0;
  if (base + 1 < n) offsets[base + 1] = run; run += v1;
  if (base + 2 < n) offsets[base + 2] = run; run += v2;
  if (base + 3 < n) offsets[base + 3] = run;
}

__global__ __launch_bounds__(256) void k_scatter(const int* __restrict__ src, const int* __restrict__ dst,
                                                 const float* __restrict__ dinv, const int* __restrict__ offsets,
                                                 int* __restrict__ cursor, int2* __restrict__ csr, int e_count) {
  int e = blockIdx.x * blockDim.x + threadIdx.x;
  if (e >= e_count) return;
  int s = src[e], d = dst[e];
  int pos = offsets[d] + atomicAdd(&cursor[d], 1);
  csr[pos] = make_int2(s, __float_as_int(dinv[s] * dinv[d]));
}

// ---- GEMM: out[r][j] = sum_k X[r][k] * W[k][j], 16 rows/block-iter, 4 rows/wave.
// If ids != nullptr, row r of X is emb[ids[r]] (fused embedding gather).
template <int K>
__global__ __launch_bounds__(256) void k_mm(const float* __restrict__ X,
                                            const int* __restrict__ ids,
                                            const float* __restrict__ emb,
                                            const float* __restrict__ W,
                                            float* __restrict__ out, int nrows) {
  __shared__ float Wlds[K * 64];
  __shared__ float xp[4][K][8];  // [wave][k][row 0..3 used; pad to 8 for banks+align]
  const int tid = threadIdx.x;
  const int lane = tid & 63;
  const int w = tid >> 6;
  for (int i = tid; i < K * 64; i += 256) Wlds[i] = W[i];
  __syncthreads();

  const int groups = (nrows + 15) >> 4;
  for (int g = blockIdx.x; g < groups; g += gridDim.x) {
    const int rbase = g << 4;
    __syncthreads();
    for (int idx = tid; idx < 16 * K; idx += 256) {
      int rr = idx / K;
      int kk = idx - rr * K;
      int r = rbase + rr;
      float v = 0.f;
      if (r < nrows) {
        const float* row = ids ? (emb + (long)ids[r] * K) : (X + (long)r * K);
        v = row[kk];
      }
      xp[rr >> 2][kk][rr & 3] = v;
    }
    __syncthreads();
    float acc0 = 0.f, acc1 = 0.f, acc2 = 0.f, acc3 = 0.f;
    #pragma unroll 8
    for (int k = 0; k < K; ++k) {
      float4 xv = *reinterpret_cast<const float4*>(&xp[w][k][0]);
      float wv = Wlds[k * 64 + lane];
      acc0 = fmaf(xv.x, wv, acc0);
      acc1 = fmaf(xv.y, wv, acc1);
      acc2 = fmaf(xv.z, wv, acc2);
      acc3 = fmaf(xv.w, wv, acc3);
    }
    int r0 = rbase + w * 4;
    if (r0 + 3 < nrows) {
      out[(long)(r0 + 0) * 64 + lane] = acc0;
      out[(long)(r0 + 1) * 64 + lane] = acc1;
      out[(long)(r0 + 2) * 64 + lane] = acc2;
      out[(long)(r0 + 3) * 64 + lane] = acc3;
    } else {
      if (r0 + 0 < nrows) out[(long)(r0 + 0) * 64 + lane] = acc0;
      if (r0 + 1 < nrows) out[(long)(r0 + 1) * 64 + lane] = acc1;
      if (r0 + 2 < nrows) out[(long)(r0 + 2) * 64 + lane] = acc2;
      if (r0 + 3 < nrows) out[(long)(r0 + 3) * 64 + lane] = acc3;
    }
  }
}

// ---- aggregation: one wave per node, lane = feature.
// out[v] = relu( xw[v]*dinv[v]^2 + b + sum_{e in in(v)} coef_e * xw[src_e] )
__global__ __launch_bounds__(256) void k_agg(const float* __restrict__ xw, const int2* __restrict__ csr,
                                             const int* __restrict__ offsets, const float* __restrict__ dinv,
                                             const float* __restrict__ bias, float* __restrict__ out, int n) {
  int v = blockIdx.x * 4 + (threadIdx.x >> 6);
  int lane = threadIdx.x & 63;
  if (v >= n) return;
  float di = dinv[v];
  float acc = fmaf(xw[(long)v * 64 + lane], di * di, bias[lane]);
  int e = offsets[v], hi = offsets[v + 1];
  for (; e + 4 <= hi; e += 4) {
    int2 r0 = csr[e], r1 = csr[e + 1], r2 = csr[e + 2], r3 = csr[e + 3];
    float v0 = xw[(long)r0.x * 64 + lane];
    float v1 = xw[(long)r1.x * 64 + lane];
    float v2 = xw[(long)r2.x * 64 + lane];
    float v3 = xw[(long)r3.x * 64 + lane];
    acc = fmaf(v0, __int_as_float(r0.y), acc);
    acc = fmaf(v1, __int_as_float(r1.y), acc);
    acc = fmaf(v2, __int_as_float(r2.y), acc);
    acc = fmaf(v3, __int_as_float(r3.y), acc);
  }
  for (; e < hi; ++e) {
    int2 r = csr[e];
    acc = fmaf(xw[(long)r.x * 64 + lane], __int_as_float(r.y), acc);
  }
  out[(long)v * 64 + lane] = fmaxf(acc, 0.f);
}

// ---- pooling (batch is sorted) + 2-layer MLP head + sigmoid, block per graph
__global__ __launch_bounds__(256) void k_pool(const float* __restrict__ x, const int* __restrict__ batch, int n,
                                              const float* __restrict__ Wf1, const float* __restrict__ bf1,
                                              const float* __restrict__ Wf2, const float* __restrict__ bf2,
                                              float* __restrict__ out) {
  int g = blockIdx.x;
  int tid = threadIdx.x, lane = tid & 63, w = tid >> 6;
  int a = 0, b = n;
  while (a < b) { int m = (a + b) >> 1; if (batch[m] < g) a = m + 1; else b = m; }
  int lo = a;
  b = n;
  while (a < b) { int m = (a + b) >> 1; if (batch[m] < g + 1) a = m + 1; else b = m; }
  int hi = a;

  float acc = 0.f;
  for (int r = lo + w; r < hi; r += 4) acc += x[(long)r * 64 + lane];
  __shared__ float red[4][64];
  __shared__ float mean[64];
  red[w][lane] = acc;
  __syncthreads();
  if (w == 0) {
    float s = red[0][lane] + red[1][lane] + red[2][lane] + red[3][lane];
    mean[lane] = s / fmaxf((float)(hi - lo), 1.0f);
  }
  __syncthreads();
  if (w == 0) {
    float h = bf1[lane];
    #pragma unroll
    for (int k = 0; k < 64; ++k) h = fmaf(mean[k], Wf1[k * 64 + lane], h);
    h = fmaxf(h, 0.f);
    float vv = h * Wf2[lane];
    for (int off = 32; off > 0; off >>= 1) vv += __shfl_down(vv, off, 64);
    if (lane == 0) out[g] = 1.0f / (1.0f + expf(-(vv + bf2[0])));
  }
}

static inline char* align256(char* p) {
  return (char*)(((uintptr_t)p + 255) & ~(uintptr_t)255);
}

extern "C" void kernel_launch(void* const* d_in, const int* in_sizes, int n_in,
                              void* d_out, int out_size, void* d_ws, size_t ws_size,
                              hipStream_t stream) {
  const int*   x_ids = (const int*)d_in[0];
  const int*   edge  = (const int*)d_in[1];
  const int*   batch = (const int*)d_in[2];
  const float* emb   = (const float*)d_in[3];
  const float* W1    = (const float*)d_in[4];
  const float* b1    = (const float*)d_in[5];
  const float* W2    = (const float*)d_in[6];
  const float* b2    = (const float*)d_in[7];
  const float* W3    = (const float*)d_in[8];
  const float* b3    = (const float*)d_in[9];
  const float* Wf1   = (const float*)d_in[10];
  const float* bf1   = (const float*)d_in[11];
  const float* Wf2   = (const float*)d_in[12];
  const float* bf2   = (const float*)d_in[13];
  float* out = (float*)d_out;

  const int N = in_sizes[0];
  const int E = in_sizes[1] / 2;
  const int G = out_size;
  const int* e_src = edge;
  const int* e_dst = edge + E;

  // workspace layout
  char* p = (char*)d_ws;
  float* bufA = (float*)p;            p = align256(p + (size_t)N * 64 * 4);
  float* bufB = (float*)p;            p = align256(p + (size_t)N * 64 * 4);
  int2*  csr  = (int2*)p;             p = align256(p + (size_t)E * 8);
  float* dinv = (float*)p;            p = align256(p + (size_t)N * 4);
  int*   cnt  = (int*)p;              p = align256(p + (size_t)N * 4);
  int*   cur  = (int*)p;              p = align256(p + (size_t)N * 4);
  int*   offs = (int*)p;              p = align256(p + (size_t)(N + 1) * 4);
  int*   bsum = (int*)p;              p = align256(p + (size_t)1024 * 4);
  (void)ws_size; (void)n_in;

  const int nb_scan = (N + 1023) / 1024;  // 98 for N=100000 (must be <= 128)
  dim3 blk(256);

  // CSR build
  k_zero<<<dim3(256), blk, 0, stream>>>(cnt, N);
  k_zero<<<dim3(256), blk, 0, stream>>>(cur, N);
  k_count<<<dim3((E + 255) / 256), blk, 0, stream>>>(e_dst, cnt, E);
  k_dinv<<<dim3((N + 255) / 256), blk, 0, stream>>>(cnt, dinv, N);
  k_scan1<<<dim3(nb_scan), blk, 0, stream>>>(cnt, N, bsum);
  k_scan2<<<dim3(1), dim3(128), 0, stream>>>(bsum, nb_scan, offs + N);
  k_scan3<<<dim3(nb_scan), blk, 0, stream>>>(cnt, N, bsum, offs);
  k_scatter<<<dim3((E + 255) / 256), blk, 0, stream>>>(e_src, e_dst, dinv, offs, cur, csr, E);

  const int agg_grid = (N + 3) / 4;

  // layer 1: xw = emb[x_ids] @ W1 ; conv+relu
  k_mm<128><<<dim3(1024), blk, 0, stream>>>(nullptr, x_ids, emb, W1, bufA, N);
  k_agg<<<dim3(agg_grid), blk, 0, stream>>>(bufA, csr, offs, dinv, b1, bufB, N);
  // layer 2
  k_mm<64><<<dim3(1024), blk, 0, stream>>>(bufB, nullptr, nullptr, W2, bufA, N);
  k_agg<<<dim3(agg_grid), blk, 0, stream>>>(bufA, csr, offs, dinv, b2, bufB, N);
  // layer 3
  k_mm<64><<<dim3(1024), blk, 0, stream>>>(bufB, nullptr, nullptr, W3, bufA, N);
  k_agg<<<dim3(agg_grid), blk, 0, stream>>>(bufA, csr, offs, dinv, b3, bufB, N);

  // pool + MLP head
  k_pool<<<dim3(G), blk, 0, stream>>>(bufB, batch, N, Wf1, bf1, Wf2, bf2, out);
}